// Round 17
// baseline (237.676 us; speedup 1.0000x reference)
//
#include <hip/hip_runtime.h>
#include <float.h>

#define BATCH 4
#define LSEQ  2048
#define DMODEL 512
#define NH    8
#define DHD   64
#define NSAMP 40
#define NTOP  40
#define NSEG  16                 // segs per bh; 16 * 128 = 2048 keys
#define SEGK  128                // keys per block
#define SUBK  64                 // keys per subtile
#define QK_SCALE 0.125f

typedef unsigned short u16;
typedef __attribute__((ext_vector_type(8))) short short8b;  // 8 bf16 = 16 B
typedef __attribute__((ext_vector_type(4))) float f32x4;
typedef __attribute__((ext_vector_type(4))) float f32x4v;

#define ASTRIDE ((size_t)BATCH * LSEQ * DMODEL)   // 4,194,304 elems (2^22)
#define WSTRIDE ((size_t)DMODEL * DMODEL)         //   262,144 elems (2^18)

// RTNE float->bf16 on raw bits (inputs finite).
static __device__ __forceinline__ u16 f2bf(float x) {
    unsigned u = __float_as_uint(x);
    u += 0x7FFFu + ((u >> 16) & 1u);
    return (u16)(u >> 16);
}
static __device__ __forceinline__ float bf2f(u16 s) {
    return __uint_as_float((unsigned)s << 16);
}
// float4 -> two bf16 planes (2-split): x = p1 + p2 + O(2^-17 |x|)
static __device__ __forceinline__ void split2(
    const float4 v, ushort4& o1, ushort4& o2)
{
    const float in[4] = {v.x, v.y, v.z, v.w};
    u16 a[4], b[4];
#pragma unroll
    for (int c = 0; c < 4; ++c) {
        a[c] = f2bf(in[c]);
        b[c] = f2bf(in[c] - bf2f(a[c]));
    }
    o1.x = a[0]; o1.y = a[1]; o1.z = a[2]; o1.w = a[3];
    o2.x = b[0]; o2.y = b[1]; o2.z = b[2]; o2.w = b[3];
}

// ---------------------------------------------------------------------------
// K0: unified 3-way bf16 split + zero-init of VmeanRaw/uacc/wsum.
// ---------------------------------------------------------------------------
__global__ __launch_bounds__(256) void split3_all(
    const float* __restrict__ x, const float* __restrict__ ctxin,
    const float* __restrict__ Wq, const float* __restrict__ Wk,
    const float* __restrict__ Wv,
    u16* __restrict__ xsP, u16* __restrict__ csP,
    u16* __restrict__ wqP, u16* __restrict__ wkP, u16* __restrict__ wvP,
    float* __restrict__ VmeanRaw, float* __restrict__ uacc,
    float* __restrict__ wsum)
{
    const int flat = blockIdx.x;
    if (flat < 8)         VmeanRaw[flat * 256 + threadIdx.x] = 0.f;      // 2048
    else if (flat < 328)  uacc[(flat - 8) * 256 + threadIdx.x] = 0.f;    // 81920
    else if (flat < 333) { const int j = (flat - 328) * 256 + threadIdx.x;
                           if (j < BATCH * NH * NTOP) wsum[j] = 0.f; }

    const int X4 = 1 << 20;
    const int W4 = 1 << 16;
    const int total = 2 * X4 + 3 * W4;
    for (int i = blockIdx.x * 256 + threadIdx.x; i < total; i += gridDim.x * 256) {
        const float* src; u16* dst; size_t pstride; int i4;
        if (i < X4)            { src = x;     dst = xsP; pstride = ASTRIDE; i4 = i; }
        else if (i < 2 * X4)   { src = ctxin; dst = csP; pstride = ASTRIDE; i4 = i - X4; }
        else {
            const int w = i - 2 * X4;
            const int which = w >> 16, rem = w & (W4 - 1);
            src = (which == 0) ? Wq : (which == 1) ? Wk : Wv;
            dst = (which == 0) ? wqP : (which == 1) ? wkP : wvP;
            pstride = WSTRIDE; i4 = rem;
        }
        const float4 v = reinterpret_cast<const float4*>(src)[i4];
        const float in[4] = {v.x, v.y, v.z, v.w};
        ushort4 o1, o2, o3;
        u16 b1[4], b2[4], b3[4];
#pragma unroll
        for (int c = 0; c < 4; ++c) {
            const float xx = in[c];
            b1[c] = f2bf(xx);
            const float r1 = xx - bf2f(b1[c]);
            b2[c] = f2bf(r1);
            b3[c] = f2bf(r1 - bf2f(b2[c]));
        }
        o1.x = b1[0]; o1.y = b1[1]; o1.z = b1[2]; o1.w = b1[3];
        o2.x = b2[0]; o2.y = b2[1]; o2.z = b2[2]; o2.w = b2[3];
        o3.x = b3[0]; o3.y = b3[1]; o3.z = b3[2]; o3.w = b3[3];
        reinterpret_cast<ushort4*>(dst)[i4]                = o1;
        reinterpret_cast<ushort4*>(dst + pstride)[i4]      = o2;
        reinterpret_cast<ushort4*>(dst + 2 * pstride)[i4]  = o3;
    }
}

// ---------------------------------------------------------------------------
// K1: unified QKV GEMM, ONE dispatch, 1D grid 768. z-INTERLEAVED decode
// (z = (i>>3)%3): every CU gets a Q/K/V mix so 6-product (Q,K) and
// 3-product (V) blocks finish together — fixes round-16's ragged tail
// (MfmaUtil 28.6%: first co-resident wave was all-QK, V backfilled).
// ---------------------------------------------------------------------------
__global__ __launch_bounds__(256) void gemm_all(
    const u16* __restrict__ xsP, const u16* __restrict__ csP,
    const u16* __restrict__ wqP, const u16* __restrict__ wkP,
    const u16* __restrict__ wvP,
    const float* __restrict__ bq, const float* __restrict__ bk,
    const float* __restrict__ bv,
    float* __restrict__ Qt, float* __restrict__ Kt, float* __restrict__ Vt,
    float* __restrict__ VmeanRaw)
{
    const int i = blockIdx.x;            // 0..767
    const int xcd = i & 7;
    const int rest = i >> 3;             // 0..95
    const int z   = rest % 3;
    const int loc = rest / 3;            // 0..31
    const int m0 = (xcd * 8 + (loc & 7)) * 128;
    const int n0 = (loc >> 3) * 128;

    const u16* __restrict__ Ap   = (z == 0) ? xsP : csP;
    const u16* __restrict__ Wp   = (z == 0) ? wqP : (z == 1 ? wkP : wvP);
    const float* __restrict__ bias = (z == 0) ? bq : (z == 1 ? bk : bv);
    float*       __restrict__ Out  = (z == 0) ? Qt : (z == 1 ? Kt : Vt);
    const int npl = (z == 2) ? 2 : 3;

    __shared__ u16 As[3][128][40];
    __shared__ u16 Ws[3][128][40];

    const int tid  = threadIdx.x;
    const int w    = tid >> 6;
    const int lane = tid & 63;
    const int wm   = w >> 1;
    const int wn   = w & 1;
    const int lr   = lane & 15;
    const int lg   = lane >> 4;

    const int srow = tid >> 1;
    const int sc   = (tid & 1) * 16;

    f32x4 acc[4][4];
#pragma unroll
    for (int mf = 0; mf < 4; ++mf)
#pragma unroll
        for (int nf = 0; nf < 4; ++nf)
#pragma unroll
            for (int r = 0; r < 4; ++r) acc[mf][nf][r] = 0.f;

    short8b sa[3][2], sw[3][2];
#pragma unroll
    for (int p = 0; p < 3; ++p) {
        if (p < npl) {
            const u16* asrc = Ap + p * ASTRIDE + (size_t)(m0 + srow) * DMODEL + sc;
            const u16* wsrc = Wp + p * WSTRIDE + (size_t)(n0 + srow) * DMODEL + sc;
            sa[p][0] = *reinterpret_cast<const short8b*>(asrc);
            sa[p][1] = *reinterpret_cast<const short8b*>(asrc + 8);
            sw[p][0] = *reinterpret_cast<const short8b*>(wsrc);
            sw[p][1] = *reinterpret_cast<const short8b*>(wsrc + 8);
        }
    }

    for (int k0 = 0; k0 < DMODEL; k0 += 32) {
#pragma unroll
        for (int p = 0; p < 3; ++p) {
            if (p < npl) {
                *reinterpret_cast<short8b*>(&As[p][srow][sc])     = sa[p][0];
                *reinterpret_cast<short8b*>(&As[p][srow][sc + 8]) = sa[p][1];
                *reinterpret_cast<short8b*>(&Ws[p][srow][sc])     = sw[p][0];
                *reinterpret_cast<short8b*>(&Ws[p][srow][sc + 8]) = sw[p][1];
            }
        }
        __syncthreads();

        if (k0 + 32 < DMODEL) {
#pragma unroll
            for (int p = 0; p < 3; ++p) {
                if (p < npl) {
                    const u16* asrc =
                        Ap + p * ASTRIDE + (size_t)(m0 + srow) * DMODEL + k0 + 32 + sc;
                    const u16* wsrc =
                        Wp + p * WSTRIDE + (size_t)(n0 + srow) * DMODEL + k0 + 32 + sc;
                    sa[p][0] = *reinterpret_cast<const short8b*>(asrc);
                    sa[p][1] = *reinterpret_cast<const short8b*>(asrc + 8);
                    sw[p][0] = *reinterpret_cast<const short8b*>(wsrc);
                    sw[p][1] = *reinterpret_cast<const short8b*>(wsrc + 8);
                }
            }
        }

        short8b af[4][3];
#pragma unroll
        for (int mf = 0; mf < 4; ++mf) {
            const int row = wm * 64 + mf * 16 + lr;
#pragma unroll
            for (int p = 0; p < 3; ++p)
                if (p < npl)
                    af[mf][p] = *reinterpret_cast<const short8b*>(&As[p][row][lg * 8]);
        }
#pragma unroll
        for (int nf = 0; nf < 4; ++nf) {
            const int row = wn * 64 + nf * 16 + lr;
            const short8b b1 = *reinterpret_cast<const short8b*>(&Ws[0][row][lg * 8]);
            const short8b b2 = *reinterpret_cast<const short8b*>(&Ws[1][row][lg * 8]);
#pragma unroll
            for (int mf = 0; mf < 4; ++mf) {
                acc[mf][nf] = __builtin_amdgcn_mfma_f32_16x16x32_bf16(af[mf][0], b1, acc[mf][nf], 0, 0, 0);
                acc[mf][nf] = __builtin_amdgcn_mfma_f32_16x16x32_bf16(af[mf][1], b1, acc[mf][nf], 0, 0, 0);
                acc[mf][nf] = __builtin_amdgcn_mfma_f32_16x16x32_bf16(af[mf][0], b2, acc[mf][nf], 0, 0, 0);
            }
            if (z != 2) {
                const short8b b3 = *reinterpret_cast<const short8b*>(&Ws[2][row][lg * 8]);
#pragma unroll
                for (int mf = 0; mf < 4; ++mf) {
                    acc[mf][nf] = __builtin_amdgcn_mfma_f32_16x16x32_bf16(af[mf][2], b1, acc[mf][nf], 0, 0, 0);
                    acc[mf][nf] = __builtin_amdgcn_mfma_f32_16x16x32_bf16(af[mf][0], b3, acc[mf][nf], 0, 0, 0);
                    acc[mf][nf] = __builtin_amdgcn_mfma_f32_16x16x32_bf16(af[mf][1], b2, acc[mf][nf], 0, 0, 0);
                }
            }
        }
        __syncthreads();
    }

#pragma unroll
    for (int nf = 0; nf < 4; ++nf) {
        const int n = n0 + wn * 64 + nf * 16 + lr;
        const int h = n >> 6, d = n & 63;
        const float bv_ = bias[n];
        float cs = 0.f;
#pragma unroll
        for (int mf = 0; mf < 4; ++mf) {
#pragma unroll
            for (int r = 0; r < 4; ++r) {
                const int m = m0 + wm * 64 + mf * 16 + lg * 4 + r;
                const int b = m >> 11, l = m & (LSEQ - 1);
                const float val = acc[mf][nf][r] + bv_;
                Out[((size_t)(b * NH + h) * LSEQ + l) * DHD + d] = val;
                cs += val;
            }
        }
        if (z == 2)
            atomicAdd(&VmeanRaw[((m0 >> 11) * NH + h) * DHD + d], cs);
    }
}

// ---------------------------------------------------------------------------
// K2: sampled sparsity measure. Runs right after gemm_all: Kt L2-warm.
// ---------------------------------------------------------------------------
__global__ __launch_bounds__(256) void score_kernel(
    const float* __restrict__ Qt, const float* __restrict__ Kt,
    const int* __restrict__ idxs, float* __restrict__ M)
{
    const int flat = blockIdx.x;
    const int xcd  = flat & 7;
    const int slot = flat >> 3;
    const int bh   = xcd * 4 + (slot >> 9);
    const int w    = threadIdx.x >> 6;
    const int lane = threadIdx.x & 63;
    const int l    = (slot & 511) * 4 + w;

    const int g  = lane >> 4;
    const int dl = lane & 15;

#if defined(__has_builtin) && __has_builtin(__builtin_nontemporal_load)
    const f32x4v q4 = __builtin_nontemporal_load(
        reinterpret_cast<const f32x4v*>(Qt + ((size_t)bh * LSEQ + l) * DHD + dl * 4));
#else
    const f32x4v q4 = *reinterpret_cast<const f32x4v*>(
        Qt + ((size_t)bh * LSEQ + l) * DHD + dl * 4);
#endif

    const float* Kb = Kt + (size_t)bh * LSEQ * DHD;
    float vmax = -FLT_MAX, vsum = 0.f;
#pragma unroll
    for (int it = 0; it < 10; ++it) {
        const int s = it * 4 + g;
        const int ks = idxs[l * NSAMP + s];
        const float4 k4 = *reinterpret_cast<const float4*>(
            Kb + (size_t)ks * DHD + dl * 4);
        float p = q4[0] * k4.x + q4[1] * k4.y + q4[2] * k4.z + q4[3] * k4.w;
        p += __shfl_xor(p, 1);
        p += __shfl_xor(p, 2);
        p += __shfl_xor(p, 4);
        p += __shfl_xor(p, 8);
        vmax = fmaxf(vmax, p);
        vsum += p;
    }
    vmax = fmaxf(vmax, __shfl_xor(vmax, 16));
    vsum += __shfl_xor(vsum, 16);
    vmax = fmaxf(vmax, __shfl_xor(vmax, 32));
    vsum += __shfl_xor(vsum, 32);
    if (lane == 0) M[(size_t)bh * LSEQ + l] = vmax - vsum * (1.0f / LSEQ);
}

// ---------------------------------------------------------------------------
// K3: stable top-40 per (b,h) (blocks 0..31) + per-batch meanout (32..35).
// ---------------------------------------------------------------------------
__global__ __launch_bounds__(256) void topk_kernel(
    const float* __restrict__ M, int* __restrict__ topidx,
    const float* __restrict__ VmeanRaw, const float* __restrict__ Wo,
    const float* __restrict__ bo, float* __restrict__ meanout)
{
    const int bh = blockIdx.x;

    if (bh >= 32) {
        const int b = bh - 32;
        __shared__ float mc[DMODEL];
        for (int i = threadIdx.x; i < DMODEL; i += 256)
            mc[i] = VmeanRaw[b * DMODEL + i] * (1.0f / (float)LSEQ);
        __syncthreads();
        for (int n = threadIdx.x; n < DMODEL; n += 256) {
            float acc = bo[n];
            const float* wr = Wo + (size_t)n * DMODEL;
            for (int k = 0; k < DMODEL; ++k) acc = fmaf(mc[k], wr[k], acc);
            meanout[b * DMODEL + n] = acc;
        }
        return;
    }

    const int w = threadIdx.x >> 6, lane = threadIdx.x & 63;
    const int base = threadIdx.x * 8;

    float e[8];
    {
        const float4 v0 = *reinterpret_cast<const float4*>(M + (size_t)bh * LSEQ + base);
        const float4 v1 = *reinterpret_cast<const float4*>(M + (size_t)bh * LSEQ + base + 4);
        e[0] = v0.x; e[1] = v0.y; e[2] = v0.z; e[3] = v0.w;
        e[4] = v1.x; e[5] = v1.y; e[6] = v1.z; e[7] = v1.w;
    }

    __shared__ float rv[4];
    __shared__ int   ri[4];
    __shared__ int   winner;

    for (int t = 0; t < NTOP; ++t) {
        float bv = e[0]; int br = 0;
#pragma unroll
        for (int r = 1; r < 8; ++r)
            if (e[r] > bv) { bv = e[r]; br = r; }
        int bi = base + br;
#pragma unroll
        for (int off = 32; off; off >>= 1) {
            const float ov = __shfl_xor(bv, off);
            const int   oi = __shfl_xor(bi, off);
            if (ov > bv || (ov == bv && oi < bi)) { bv = ov; bi = oi; }
        }
        if (lane == 0) { rv[w] = bv; ri[w] = bi; }
        __syncthreads();
        if (threadIdx.x == 0) {
            float fv = rv[0]; int fi = ri[0];
#pragma unroll
            for (int k = 1; k < 4; ++k)
                if (rv[k] > fv || (rv[k] == fv && ri[k] < fi)) { fv = rv[k]; fi = ri[k]; }
            topidx[bh * NTOP + t] = fi;
            winner = fi;
        }
        __syncthreads();
        const int fi = winner;
        if ((fi >> 3) == threadIdx.x) e[fi & 7] = -FLT_MAX;
    }
}

// ---------------------------------------------------------------------------
// K4: attention partials on MFMA + out-broadcast epilogue (meanout ready
// since topk; each of the 512 blocks streams a 32 KB slice of `out`,
// replacing the finalize_base dispatch).
// ---------------------------------------------------------------------------
__global__ __launch_bounds__(256) void attn_partial(
    const float* __restrict__ Qt, const float* __restrict__ Kt,
    const float* __restrict__ Vt, const int* __restrict__ topidx,
    float* __restrict__ wsum, float* __restrict__ uacc,
    const float* __restrict__ meanout, float* __restrict__ out)
{
    const int bh  = blockIdx.x;
    const int seg = blockIdx.y;
    const int tid = threadIdx.x;
    const int w    = tid >> 6;
    const int lane = tid & 63;
    const int lr = lane & 15, lg = lane >> 4;

    __shared__ u16 Qs[2][48][72];
    __shared__ u16 Ks[2][64][72];
    __shared__ u16 Vtl[2][64][72];
    __shared__ float wsl[48];

    for (int i = tid; i < 48 * 16; i += 256) {
        const int row = i >> 4, c = i & 15;
        float4 v = make_float4(0.f, 0.f, 0.f, 0.f);
        if (row < NTOP) {
            const int l = topidx[bh * NTOP + row];
            v = *reinterpret_cast<const float4*>(
                Qt + ((size_t)bh * LSEQ + l) * DHD + c * 4);
        }
        ushort4 o1, o2;
        split2(v, o1, o2);
        *reinterpret_cast<ushort4*>(&Qs[0][row][c * 4]) = o1;
        *reinterpret_cast<ushort4*>(&Qs[1][row][c * 4]) = o2;
    }
    if (tid < 48) wsl[tid] = 0.f;

    f32x4 pvacc[3];
#pragma unroll
    for (int qt = 0; qt < 3; ++qt)
#pragma unroll
        for (int r = 0; r < 4; ++r) pvacc[qt][r] = 0.f;

    for (int sub = 0; sub < 2; ++sub) {
        const int kbase = seg * SEGK + sub * SUBK;
        __syncthreads();

        for (int i = tid; i < 64 * 16; i += 256) {
            const int key = i >> 4, c = i & 15;
            const size_t g = ((size_t)bh * LSEQ + kbase + key) * DHD + c * 4;
            const float4 kv = *reinterpret_cast<const float4*>(Kt + g);
            const float4 vv = *reinterpret_cast<const float4*>(Vt + g);
            ushort4 k1, k2, v1, v2;
            split2(kv, k1, k2);
            split2(vv, v1, v2);
            *reinterpret_cast<ushort4*>(&Ks[0][key][c * 4]) = k1;
            *reinterpret_cast<ushort4*>(&Ks[1][key][c * 4]) = k2;
            Vtl[0][c * 4 + 0][key] = v1.x; Vtl[0][c * 4 + 1][key] = v1.y;
            Vtl[0][c * 4 + 2][key] = v1.z; Vtl[0][c * 4 + 3][key] = v1.w;
            Vtl[1][c * 4 + 0][key] = v2.x; Vtl[1][c * 4 + 1][key] = v2.y;
            Vtl[1][c * 4 + 2][key] = v2.z; Vtl[1][c * 4 + 3][key] = v2.w;
        }
        __syncthreads();

        f32x4 acc[3];
#pragma unroll
        for (int qt = 0; qt < 3; ++qt)
#pragma unroll
            for (int r = 0; r < 4; ++r) acc[qt][r] = 0.f;
#pragma unroll
        for (int ks = 0; ks < 2; ++ks) {
            const short8b b1 = *reinterpret_cast<const short8b*>(
                &Ks[0][w * 16 + lr][ks * 32 + lg * 8]);
            const short8b b2 = *reinterpret_cast<const short8b*>(
                &Ks[1][w * 16 + lr][ks * 32 + lg * 8]);
#pragma unroll
            for (int qt = 0; qt < 3; ++qt) {
                const short8b a1 = *reinterpret_cast<const short8b*>(
                    &Qs[0][qt * 16 + lr][ks * 32 + lg * 8]);
                const short8b a2 = *reinterpret_cast<const short8b*>(
                    &Qs[1][qt * 16 + lr][ks * 32 + lg * 8]);
                acc[qt] = __builtin_amdgcn_mfma_f32_16x16x32_bf16(a1, b1, acc[qt], 0, 0, 0);
                acc[qt] = __builtin_amdgcn_mfma_f32_16x16x32_bf16(a2, b1, acc[qt], 0, 0, 0);
                acc[qt] = __builtin_amdgcn_mfma_f32_16x16x32_bf16(a1, b2, acc[qt], 0, 0, 0);
            }
        }
        __syncthreads();

#pragma unroll
        for (int qt = 0; qt < 3; ++qt) {
#pragma unroll
            for (int r = 0; r < 4; ++r) {
                const float e = __expf(acc[qt][r] * QK_SCALE);
                float s = e;
                s += __shfl_xor(s, 1);
                s += __shfl_xor(s, 2);
                s += __shfl_xor(s, 4);
                s += __shfl_xor(s, 8);
                const int q = qt * 16 + lg * 4 + r;
                if (lr == 0) atomicAdd(&wsl[q], s);
                const u16 p1 = f2bf(e);
                const u16 p2 = f2bf(e - bf2f(p1));
                Ks[0][q][w * 16 + lr] = p1;
                Ks[1][q][w * 16 + lr] = p2;
            }
        }
        __syncthreads();

#pragma unroll
        for (int ks = 0; ks < 2; ++ks) {
            const short8b b1 = *reinterpret_cast<const short8b*>(
                &Vtl[0][w * 16 + lr][ks * 32 + lg * 8]);
            const short8b b2 = *reinterpret_cast<const short8b*>(
                &Vtl[1][w * 16 + lr][ks * 32 + lg * 8]);
#pragma unroll
            for (int qt = 0; qt < 3; ++qt) {
                const short8b a1 = *reinterpret_cast<const short8b*>(
                    &Ks[0][qt * 16 + lr][ks * 32 + lg * 8]);
                const short8b a2 = *reinterpret_cast<const short8b*>(
                    &Ks[1][qt * 16 + lr][ks * 32 + lg * 8]);
                pvacc[qt] = __builtin_amdgcn_mfma_f32_16x16x32_bf16(a1, b1, pvacc[qt], 0, 0, 0);
                pvacc[qt] = __builtin_amdgcn_mfma_f32_16x16x32_bf16(a2, b1, pvacc[qt], 0, 0, 0);
                pvacc[qt] = __builtin_amdgcn_mfma_f32_16x16x32_bf16(a1, b2, pvacc[qt], 0, 0, 0);
            }
        }
    }

#pragma unroll
    for (int qt = 0; qt < 3; ++qt) {
#pragma unroll
        for (int r = 0; r < 4; ++r) {
            const int q = qt * 16 + lg * 4 + r;
            if (q < NTOP)
                atomicAdd(&uacc[((size_t)bh * NTOP + q) * DHD + w * 16 + lr],
                          pvacc[qt][r]);
        }
    }
    if (tid < NTOP) atomicAdd(&wsum[bh * NTOP + tid], wsl[tid]);

    // out-broadcast epilogue: block (bh,seg) streams its 2048-float4 slice
    {
        const int blkid = bh * NSEG + seg;               // 0..511
        const int base4 = blkid * 2048;                  // of 2^20 total
        for (int i = base4 + tid; i < base4 + 2048; i += 256) {
            const int row = i >> 7;
            const int b = row >> 11;
            const int c = i & 127;
            reinterpret_cast<float4*>(out)[i] =
                reinterpret_cast<const float4*>(meanout)[b * 128 + c];
        }
    }
}

// ---------------------------------------------------------------------------
// K5: scatter-add selected rows: out[b,l,:] += delta @ Wo_h^T, where delta
// is computed INLINE from uacc/wsum/VmeanRaw (finalize fused away).
// ---------------------------------------------------------------------------
__global__ __launch_bounds__(128) void out_scatter(
    const int* __restrict__ topidx, const float* __restrict__ wsum,
    const float* __restrict__ uacc, const float* __restrict__ VmeanRaw,
    const float* __restrict__ Wo, float* __restrict__ out)
{
    const int bh = blockIdx.x;
    const int u  = blockIdx.y;
    const int b = bh >> 3, h = bh & 7;
    const int l = topidx[bh * NTOP + u];

    __shared__ float dl[DHD];
    if (threadIdx.x < DHD) {
        const float inv = 1.0f / wsum[bh * NTOP + u];
        const float vm = VmeanRaw[bh * DHD + threadIdx.x] * (1.0f / (float)LSEQ);
        dl[threadIdx.x] =
            uacc[((size_t)bh * NTOP + u) * DHD + threadIdx.x] * inv - vm;
    }
    __syncthreads();

    float* orow = out + ((size_t)b * LSEQ + l) * DMODEL;
#pragma unroll
    for (int c = 0; c < 4; ++c) {
        const int n = threadIdx.x * 4 + c;
        const float4* wr4 = reinterpret_cast<const float4*>(
            Wo + (size_t)n * DMODEL + h * DHD);
        float a = 0.f;
#pragma unroll
        for (int dd = 0; dd < 16; ++dd) {
            const float4 wv = wr4[dd];
            a += dl[dd * 4 + 0] * wv.x + dl[dd * 4 + 1] * wv.y +
                 dl[dd * 4 + 2] * wv.z + dl[dd * 4 + 3] * wv.w;
        }
        atomicAdd(&orow[n], a);
    }
}

// ---------------------------------------------------------------------------
extern "C" void kernel_launch(void* const* d_in, const int* in_sizes, int n_in,
                              void* d_out, int out_size, void* d_ws, size_t ws_size,
                              hipStream_t stream)
{
    (void)in_sizes; (void)n_in; (void)out_size; (void)ws_size;
    const float* x     = (const float*)d_in[0];
    const float* ctxin = (const float*)d_in[1];
    const float* Wq    = (const float*)d_in[2];
    const float* bq    = (const float*)d_in[3];
    const float* Wk    = (const float*)d_in[4];
    const float* bk    = (const float*)d_in[5];
    const float* Wv    = (const float*)d_in[6];
    const float* bv    = (const float*)d_in[7];
    const float* Wo    = (const float*)d_in[8];
    const float* bo    = (const float*)d_in[9];
    const int*   idxs  = (const int*)d_in[10];
    float* out = (float*)d_out;

    char* ws = (char*)d_ws;
    size_t off = 0;
    auto alloc = [&](size_t bytes) -> void* {
        void* p = ws + off;
        off += (bytes + 255) & ~(size_t)255;
        return p;
    };

    const size_t qkv_bytes = (size_t)BATCH * NH * LSEQ * DHD * sizeof(float);
    float*         Qt       = (float*)alloc(qkv_bytes);
    float*         Kt       = (float*)alloc(qkv_bytes);
    float*         Vt       = (float*)alloc(qkv_bytes);
    float*         Mbuf     = (float*)alloc((size_t)BATCH * NH * LSEQ * sizeof(float));
    float*         VmeanRaw = (float*)alloc((size_t)BATCH * NH * DHD * sizeof(float));
    float*         meanout  = (float*)alloc((size_t)BATCH * DMODEL * sizeof(float));
    int*           topidx   = (int*)alloc((size_t)BATCH * NH * NTOP * sizeof(int));
    float*         wsum     = (float*)alloc((size_t)BATCH * NH * NTOP * sizeof(float));
    float*         uacc     = (float*)alloc((size_t)BATCH * NH * NTOP * DHD * sizeof(float));
    u16*           xsP      = (u16*)alloc(ASTRIDE * 3 * 2);
    u16*           csP      = (u16*)alloc(ASTRIDE * 3 * 2);
    u16*           wqP      = (u16*)alloc(WSTRIDE * 3 * 2);
    u16*           wkP      = (u16*)alloc(WSTRIDE * 3 * 2);
    u16*           wvP      = (u16*)alloc(WSTRIDE * 3 * 2);

    split3_all<<<2048, 256, 0, stream>>>(x, ctxin, Wq, Wk, Wv,
                                         xsP, csP, wqP, wkP, wvP,
                                         VmeanRaw, uacc, wsum);

    gemm_all<<<768, 256, 0, stream>>>(
        xsP, csP, wqP, wkP, wvP, bq, bk, bv, Qt, Kt, Vt, VmeanRaw);

    score_kernel<<<(BATCH * NH * LSEQ) / 4, 256, 0, stream>>>(
        Qt, Kt, idxs, Mbuf);

    topk_kernel<<<36, 256, 0, stream>>>(
        Mbuf, topidx, VmeanRaw, Wo, bo, meanout);

    attn_partial<<<dim3(BATCH * NH, NSEG), 256, 0, stream>>>(
        Qt, Kt, Vt, topidx, wsum, uacc, meanout, out);

    out_scatter<<<dim3(BATCH * NH, NTOP), 128, 0, stream>>>(
        topidx, wsum, uacc, VmeanRaw, Wo, out);
}

// Round 18
// 224.078 us; speedup vs baseline: 1.0607x; 1.0607x over previous
//
#include <hip/hip_runtime.h>
#include <float.h>

#define BATCH 4
#define LSEQ  2048
#define DMODEL 512
#define NH    8
#define DHD   64
#define NSAMP 40
#define NTOP  40
#define NSEG  16                 // segs per bh; 16 * 128 = 2048 keys
#define SEGK  128                // keys per block
#define SUBK  64                 // keys per subtile
#define QK_SCALE 0.125f

typedef unsigned short u16;
typedef __attribute__((ext_vector_type(8))) short short8b;  // 8 bf16 = 16 B
typedef __attribute__((ext_vector_type(4))) float f32x4;
typedef __attribute__((ext_vector_type(4))) float f32x4v;

#define ASTRIDE ((size_t)BATCH * LSEQ * DMODEL)   // 4,194,304 elems (2^22)
#define WSTRIDE ((size_t)DMODEL * DMODEL)         //   262,144 elems (2^18)

// RTNE float->bf16 on raw bits (inputs finite).
static __device__ __forceinline__ u16 f2bf(float x) {
    unsigned u = __float_as_uint(x);
    u += 0x7FFFu + ((u >> 16) & 1u);
    return (u16)(u >> 16);
}
static __device__ __forceinline__ float bf2f(u16 s) {
    return __uint_as_float((unsigned)s << 16);
}
// float4 -> two bf16 planes (2-split): x = p1 + p2 + O(2^-17 |x|)
static __device__ __forceinline__ void split2(
    const float4 v, ushort4& o1, ushort4& o2)
{
    const float in[4] = {v.x, v.y, v.z, v.w};
    u16 a[4], b[4];
#pragma unroll
    for (int c = 0; c < 4; ++c) {
        a[c] = f2bf(in[c]);
        b[c] = f2bf(in[c] - bf2f(a[c]));
    }
    o1.x = a[0]; o1.y = a[1]; o1.z = a[2]; o1.w = a[3];
    o2.x = b[0]; o2.y = b[1]; o2.z = b[2]; o2.w = b[3];
}

// ---------------------------------------------------------------------------
// K0: unified 3-way bf16 split + zero-init of VmeanRaw/uacc/wsum.
// ---------------------------------------------------------------------------
__global__ __launch_bounds__(256) void split3_all(
    const float* __restrict__ x, const float* __restrict__ ctxin,
    const float* __restrict__ Wq, const float* __restrict__ Wk,
    const float* __restrict__ Wv,
    u16* __restrict__ xsP, u16* __restrict__ csP,
    u16* __restrict__ wqP, u16* __restrict__ wkP, u16* __restrict__ wvP,
    float* __restrict__ VmeanRaw, float* __restrict__ uacc,
    float* __restrict__ wsum)
{
    const int flat = blockIdx.x;
    if (flat < 8)         VmeanRaw[flat * 256 + threadIdx.x] = 0.f;      // 2048
    else if (flat < 328)  uacc[(flat - 8) * 256 + threadIdx.x] = 0.f;    // 81920
    else if (flat < 333) { const int j = (flat - 328) * 256 + threadIdx.x;
                           if (j < BATCH * NH * NTOP) wsum[j] = 0.f; }

    const int X4 = 1 << 20;
    const int W4 = 1 << 16;
    const int total = 2 * X4 + 3 * W4;
    for (int i = blockIdx.x * 256 + threadIdx.x; i < total; i += gridDim.x * 256) {
        const float* src; u16* dst; size_t pstride; int i4;
        if (i < X4)            { src = x;     dst = xsP; pstride = ASTRIDE; i4 = i; }
        else if (i < 2 * X4)   { src = ctxin; dst = csP; pstride = ASTRIDE; i4 = i - X4; }
        else {
            const int w = i - 2 * X4;
            const int which = w >> 16, rem = w & (W4 - 1);
            src = (which == 0) ? Wq : (which == 1) ? Wk : Wv;
            dst = (which == 0) ? wqP : (which == 1) ? wkP : wvP;
            pstride = WSTRIDE; i4 = rem;
        }
        const float4 v = reinterpret_cast<const float4*>(src)[i4];
        const float in[4] = {v.x, v.y, v.z, v.w};
        ushort4 o1, o2, o3;
        u16 b1[4], b2[4], b3[4];
#pragma unroll
        for (int c = 0; c < 4; ++c) {
            const float xx = in[c];
            b1[c] = f2bf(xx);
            const float r1 = xx - bf2f(b1[c]);
            b2[c] = f2bf(r1);
            b3[c] = f2bf(r1 - bf2f(b2[c]));
        }
        o1.x = b1[0]; o1.y = b1[1]; o1.z = b1[2]; o1.w = b1[3];
        o2.x = b2[0]; o2.y = b2[1]; o2.z = b2[2]; o2.w = b2[3];
        o3.x = b3[0]; o3.y = b3[1]; o3.z = b3[2]; o3.w = b3[3];
        reinterpret_cast<ushort4*>(dst)[i4]                = o1;
        reinterpret_cast<ushort4*>(dst + pstride)[i4]      = o2;
        reinterpret_cast<ushort4*>(dst + 2 * pstride)[i4]  = o3;
    }
}

// ---------------------------------------------------------------------------
// K1: unified QKV GEMM, grid (256, 3), z = blockIdx.y. REVERTED from the
// round-17 z-interleave: mixing z on one XCD doubled the L2 working set
// (FETCH 49->84 MB, MfmaUtil 25%). x-fastest dispatch keeps all z=0 blocks
// co-resident -> each XCD's L2 holds ONE A-panel set + one weight matrix.
// ---------------------------------------------------------------------------
__global__ __launch_bounds__(256) void gemm_all(
    const u16* __restrict__ xsP, const u16* __restrict__ csP,
    const u16* __restrict__ wqP, const u16* __restrict__ wkP,
    const u16* __restrict__ wvP,
    const float* __restrict__ bq, const float* __restrict__ bk,
    const float* __restrict__ bv,
    float* __restrict__ Qt, float* __restrict__ Kt, float* __restrict__ Vt,
    float* __restrict__ VmeanRaw)
{
    const int z = blockIdx.y;
    const int i = blockIdx.x;
    const int xcd = i & 7;
    const int loc = i >> 3;
    const int m0 = (xcd * 8 + (loc & 7)) * 128;
    const int n0 = (loc >> 3) * 128;

    const u16* __restrict__ Ap   = (z == 0) ? xsP : csP;
    const u16* __restrict__ Wp   = (z == 0) ? wqP : (z == 1 ? wkP : wvP);
    const float* __restrict__ bias = (z == 0) ? bq : (z == 1 ? bk : bv);
    float*       __restrict__ Out  = (z == 0) ? Qt : (z == 1 ? Kt : Vt);
    const int npl = (z == 2) ? 2 : 3;

    __shared__ u16 As[3][128][40];
    __shared__ u16 Ws[3][128][40];

    const int tid  = threadIdx.x;
    const int w    = tid >> 6;
    const int lane = tid & 63;
    const int wm   = w >> 1;
    const int wn   = w & 1;
    const int lr   = lane & 15;
    const int lg   = lane >> 4;

    const int srow = tid >> 1;
    const int sc   = (tid & 1) * 16;

    f32x4 acc[4][4];
#pragma unroll
    for (int mf = 0; mf < 4; ++mf)
#pragma unroll
        for (int nf = 0; nf < 4; ++nf)
#pragma unroll
            for (int r = 0; r < 4; ++r) acc[mf][nf][r] = 0.f;

    short8b sa[3][2], sw[3][2];
#pragma unroll
    for (int p = 0; p < 3; ++p) {
        if (p < npl) {
            const u16* asrc = Ap + p * ASTRIDE + (size_t)(m0 + srow) * DMODEL + sc;
            const u16* wsrc = Wp + p * WSTRIDE + (size_t)(n0 + srow) * DMODEL + sc;
            sa[p][0] = *reinterpret_cast<const short8b*>(asrc);
            sa[p][1] = *reinterpret_cast<const short8b*>(asrc + 8);
            sw[p][0] = *reinterpret_cast<const short8b*>(wsrc);
            sw[p][1] = *reinterpret_cast<const short8b*>(wsrc + 8);
        }
    }

    for (int k0 = 0; k0 < DMODEL; k0 += 32) {
#pragma unroll
        for (int p = 0; p < 3; ++p) {
            if (p < npl) {
                *reinterpret_cast<short8b*>(&As[p][srow][sc])     = sa[p][0];
                *reinterpret_cast<short8b*>(&As[p][srow][sc + 8]) = sa[p][1];
                *reinterpret_cast<short8b*>(&Ws[p][srow][sc])     = sw[p][0];
                *reinterpret_cast<short8b*>(&Ws[p][srow][sc + 8]) = sw[p][1];
            }
        }
        __syncthreads();

        if (k0 + 32 < DMODEL) {
#pragma unroll
            for (int p = 0; p < 3; ++p) {
                if (p < npl) {
                    const u16* asrc =
                        Ap + p * ASTRIDE + (size_t)(m0 + srow) * DMODEL + k0 + 32 + sc;
                    const u16* wsrc =
                        Wp + p * WSTRIDE + (size_t)(n0 + srow) * DMODEL + k0 + 32 + sc;
                    sa[p][0] = *reinterpret_cast<const short8b*>(asrc);
                    sa[p][1] = *reinterpret_cast<const short8b*>(asrc + 8);
                    sw[p][0] = *reinterpret_cast<const short8b*>(wsrc);
                    sw[p][1] = *reinterpret_cast<const short8b*>(wsrc + 8);
                }
            }
        }

        short8b af[4][3];
#pragma unroll
        for (int mf = 0; mf < 4; ++mf) {
            const int row = wm * 64 + mf * 16 + lr;
#pragma unroll
            for (int p = 0; p < 3; ++p)
                if (p < npl)
                    af[mf][p] = *reinterpret_cast<const short8b*>(&As[p][row][lg * 8]);
        }
#pragma unroll
        for (int nf = 0; nf < 4; ++nf) {
            const int row = wn * 64 + nf * 16 + lr;
            const short8b b1 = *reinterpret_cast<const short8b*>(&Ws[0][row][lg * 8]);
            const short8b b2 = *reinterpret_cast<const short8b*>(&Ws[1][row][lg * 8]);
#pragma unroll
            for (int mf = 0; mf < 4; ++mf) {
                acc[mf][nf] = __builtin_amdgcn_mfma_f32_16x16x32_bf16(af[mf][0], b1, acc[mf][nf], 0, 0, 0);
                acc[mf][nf] = __builtin_amdgcn_mfma_f32_16x16x32_bf16(af[mf][1], b1, acc[mf][nf], 0, 0, 0);
                acc[mf][nf] = __builtin_amdgcn_mfma_f32_16x16x32_bf16(af[mf][0], b2, acc[mf][nf], 0, 0, 0);
            }
            if (z != 2) {
                const short8b b3 = *reinterpret_cast<const short8b*>(&Ws[2][row][lg * 8]);
#pragma unroll
                for (int mf = 0; mf < 4; ++mf) {
                    acc[mf][nf] = __builtin_amdgcn_mfma_f32_16x16x32_bf16(af[mf][2], b1, acc[mf][nf], 0, 0, 0);
                    acc[mf][nf] = __builtin_amdgcn_mfma_f32_16x16x32_bf16(af[mf][0], b3, acc[mf][nf], 0, 0, 0);
                    acc[mf][nf] = __builtin_amdgcn_mfma_f32_16x16x32_bf16(af[mf][1], b2, acc[mf][nf], 0, 0, 0);
                }
            }
        }
        __syncthreads();
    }

#pragma unroll
    for (int nf = 0; nf < 4; ++nf) {
        const int n = n0 + wn * 64 + nf * 16 + lr;
        const int h = n >> 6, d = n & 63;
        const float bv_ = bias[n];
        float cs = 0.f;
#pragma unroll
        for (int mf = 0; mf < 4; ++mf) {
#pragma unroll
            for (int r = 0; r < 4; ++r) {
                const int m = m0 + wm * 64 + mf * 16 + lg * 4 + r;
                const int b = m >> 11, l = m & (LSEQ - 1);
                const float val = acc[mf][nf][r] + bv_;
                Out[((size_t)(b * NH + h) * LSEQ + l) * DHD + d] = val;
                cs += val;
            }
        }
        if (z == 2)
            atomicAdd(&VmeanRaw[((m0 >> 11) * NH + h) * DHD + d], cs);
    }
}

// ---------------------------------------------------------------------------
// K2: sampled sparsity measure. Runs right after gemm_all: Kt L2-warm.
// ---------------------------------------------------------------------------
__global__ __launch_bounds__(256) void score_kernel(
    const float* __restrict__ Qt, const float* __restrict__ Kt,
    const int* __restrict__ idxs, float* __restrict__ M)
{
    const int flat = blockIdx.x;
    const int xcd  = flat & 7;
    const int slot = flat >> 3;
    const int bh   = xcd * 4 + (slot >> 9);
    const int w    = threadIdx.x >> 6;
    const int lane = threadIdx.x & 63;
    const int l    = (slot & 511) * 4 + w;

    const int g  = lane >> 4;
    const int dl = lane & 15;

#if defined(__has_builtin) && __has_builtin(__builtin_nontemporal_load)
    const f32x4v q4 = __builtin_nontemporal_load(
        reinterpret_cast<const f32x4v*>(Qt + ((size_t)bh * LSEQ + l) * DHD + dl * 4));
#else
    const f32x4v q4 = *reinterpret_cast<const f32x4v*>(
        Qt + ((size_t)bh * LSEQ + l) * DHD + dl * 4);
#endif

    const float* Kb = Kt + (size_t)bh * LSEQ * DHD;
    float vmax = -FLT_MAX, vsum = 0.f;
#pragma unroll
    for (int it = 0; it < 10; ++it) {
        const int s = it * 4 + g;
        const int ks = idxs[l * NSAMP + s];
        const float4 k4 = *reinterpret_cast<const float4*>(
            Kb + (size_t)ks * DHD + dl * 4);
        float p = q4[0] * k4.x + q4[1] * k4.y + q4[2] * k4.z + q4[3] * k4.w;
        p += __shfl_xor(p, 1);
        p += __shfl_xor(p, 2);
        p += __shfl_xor(p, 4);
        p += __shfl_xor(p, 8);
        vmax = fmaxf(vmax, p);
        vsum += p;
    }
    vmax = fmaxf(vmax, __shfl_xor(vmax, 16));
    vsum += __shfl_xor(vsum, 16);
    vmax = fmaxf(vmax, __shfl_xor(vmax, 32));
    vsum += __shfl_xor(vsum, 32);
    if (lane == 0) M[(size_t)bh * LSEQ + l] = vmax - vsum * (1.0f / LSEQ);
}

// ---------------------------------------------------------------------------
// K3: stable top-40 per (b,h) (blocks 0..31) + per-batch meanout (32..35).
// ---------------------------------------------------------------------------
__global__ __launch_bounds__(256) void topk_kernel(
    const float* __restrict__ M, int* __restrict__ topidx,
    const float* __restrict__ VmeanRaw, const float* __restrict__ Wo,
    const float* __restrict__ bo, float* __restrict__ meanout)
{
    const int bh = blockIdx.x;

    if (bh >= 32) {
        const int b = bh - 32;
        __shared__ float mc[DMODEL];
        for (int i = threadIdx.x; i < DMODEL; i += 256)
            mc[i] = VmeanRaw[b * DMODEL + i] * (1.0f / (float)LSEQ);
        __syncthreads();
        for (int n = threadIdx.x; n < DMODEL; n += 256) {
            float acc = bo[n];
            const float* wr = Wo + (size_t)n * DMODEL;
            for (int k = 0; k < DMODEL; ++k) acc = fmaf(mc[k], wr[k], acc);
            meanout[b * DMODEL + n] = acc;
        }
        return;
    }

    const int w = threadIdx.x >> 6, lane = threadIdx.x & 63;
    const int base = threadIdx.x * 8;

    float e[8];
    {
        const float4 v0 = *reinterpret_cast<const float4*>(M + (size_t)bh * LSEQ + base);
        const float4 v1 = *reinterpret_cast<const float4*>(M + (size_t)bh * LSEQ + base + 4);
        e[0] = v0.x; e[1] = v0.y; e[2] = v0.z; e[3] = v0.w;
        e[4] = v1.x; e[5] = v1.y; e[6] = v1.z; e[7] = v1.w;
    }

    __shared__ float rv[4];
    __shared__ int   ri[4];
    __shared__ int   winner;

    for (int t = 0; t < NTOP; ++t) {
        float bv = e[0]; int br = 0;
#pragma unroll
        for (int r = 1; r < 8; ++r)
            if (e[r] > bv) { bv = e[r]; br = r; }
        int bi = base + br;
#pragma unroll
        for (int off = 32; off; off >>= 1) {
            const float ov = __shfl_xor(bv, off);
            const int   oi = __shfl_xor(bi, off);
            if (ov > bv || (ov == bv && oi < bi)) { bv = ov; bi = oi; }
        }
        if (lane == 0) { rv[w] = bv; ri[w] = bi; }
        __syncthreads();
        if (threadIdx.x == 0) {
            float fv = rv[0]; int fi = ri[0];
#pragma unroll
            for (int k = 1; k < 4; ++k)
                if (rv[k] > fv || (rv[k] == fv && ri[k] < fi)) { fv = rv[k]; fi = ri[k]; }
            topidx[bh * NTOP + t] = fi;
            winner = fi;
        }
        __syncthreads();
        const int fi = winner;
        if ((fi >> 3) == threadIdx.x) e[fi & 7] = -FLT_MAX;
    }
}

// ---------------------------------------------------------------------------
// K4: attention partials on MFMA + out-broadcast epilogue.
// ---------------------------------------------------------------------------
__global__ __launch_bounds__(256) void attn_partial(
    const float* __restrict__ Qt, const float* __restrict__ Kt,
    const float* __restrict__ Vt, const int* __restrict__ topidx,
    float* __restrict__ wsum, float* __restrict__ uacc,
    const float* __restrict__ meanout, float* __restrict__ out)
{
    const int bh  = blockIdx.x;
    const int seg = blockIdx.y;
    const int tid = threadIdx.x;
    const int w    = tid >> 6;
    const int lane = tid & 63;
    const int lr = lane & 15, lg = lane >> 4;

    __shared__ u16 Qs[2][48][72];
    __shared__ u16 Ks[2][64][72];
    __shared__ u16 Vtl[2][64][72];
    __shared__ float wsl[48];

    for (int i = tid; i < 48 * 16; i += 256) {
        const int row = i >> 4, c = i & 15;
        float4 v = make_float4(0.f, 0.f, 0.f, 0.f);
        if (row < NTOP) {
            const int l = topidx[bh * NTOP + row];
            v = *reinterpret_cast<const float4*>(
                Qt + ((size_t)bh * LSEQ + l) * DHD + c * 4);
        }
        ushort4 o1, o2;
        split2(v, o1, o2);
        *reinterpret_cast<ushort4*>(&Qs[0][row][c * 4]) = o1;
        *reinterpret_cast<ushort4*>(&Qs[1][row][c * 4]) = o2;
    }
    if (tid < 48) wsl[tid] = 0.f;

    f32x4 pvacc[3];
#pragma unroll
    for (int qt = 0; qt < 3; ++qt)
#pragma unroll
        for (int r = 0; r < 4; ++r) pvacc[qt][r] = 0.f;

    for (int sub = 0; sub < 2; ++sub) {
        const int kbase = seg * SEGK + sub * SUBK;
        __syncthreads();

        for (int i = tid; i < 64 * 16; i += 256) {
            const int key = i >> 4, c = i & 15;
            const size_t g = ((size_t)bh * LSEQ + kbase + key) * DHD + c * 4;
            const float4 kv = *reinterpret_cast<const float4*>(Kt + g);
            const float4 vv = *reinterpret_cast<const float4*>(Vt + g);
            ushort4 k1, k2, v1, v2;
            split2(kv, k1, k2);
            split2(vv, v1, v2);
            *reinterpret_cast<ushort4*>(&Ks[0][key][c * 4]) = k1;
            *reinterpret_cast<ushort4*>(&Ks[1][key][c * 4]) = k2;
            Vtl[0][c * 4 + 0][key] = v1.x; Vtl[0][c * 4 + 1][key] = v1.y;
            Vtl[0][c * 4 + 2][key] = v1.z; Vtl[0][c * 4 + 3][key] = v1.w;
            Vtl[1][c * 4 + 0][key] = v2.x; Vtl[1][c * 4 + 1][key] = v2.y;
            Vtl[1][c * 4 + 2][key] = v2.z; Vtl[1][c * 4 + 3][key] = v2.w;
        }
        __syncthreads();

        f32x4 acc[3];
#pragma unroll
        for (int qt = 0; qt < 3; ++qt)
#pragma unroll
            for (int r = 0; r < 4; ++r) acc[qt][r] = 0.f;
#pragma unroll
        for (int ks = 0; ks < 2; ++ks) {
            const short8b b1 = *reinterpret_cast<const short8b*>(
                &Ks[0][w * 16 + lr][ks * 32 + lg * 8]);
            const short8b b2 = *reinterpret_cast<const short8b*>(
                &Ks[1][w * 16 + lr][ks * 32 + lg * 8]);
#pragma unroll
            for (int qt = 0; qt < 3; ++qt) {
                const short8b a1 = *reinterpret_cast<const short8b*>(
                    &Qs[0][qt * 16 + lr][ks * 32 + lg * 8]);
                const short8b a2 = *reinterpret_cast<const short8b*>(
                    &Qs[1][qt * 16 + lr][ks * 32 + lg * 8]);
                acc[qt] = __builtin_amdgcn_mfma_f32_16x16x32_bf16(a1, b1, acc[qt], 0, 0, 0);
                acc[qt] = __builtin_amdgcn_mfma_f32_16x16x32_bf16(a2, b1, acc[qt], 0, 0, 0);
                acc[qt] = __builtin_amdgcn_mfma_f32_16x16x32_bf16(a1, b2, acc[qt], 0, 0, 0);
            }
        }
        __syncthreads();

#pragma unroll
        for (int qt = 0; qt < 3; ++qt) {
#pragma unroll
            for (int r = 0; r < 4; ++r) {
                const float e = __expf(acc[qt][r] * QK_SCALE);
                float s = e;
                s += __shfl_xor(s, 1);
                s += __shfl_xor(s, 2);
                s += __shfl_xor(s, 4);
                s += __shfl_xor(s, 8);
                const int q = qt * 16 + lg * 4 + r;
                if (lr == 0) atomicAdd(&wsl[q], s);
                const u16 p1 = f2bf(e);
                const u16 p2 = f2bf(e - bf2f(p1));
                Ks[0][q][w * 16 + lr] = p1;
                Ks[1][q][w * 16 + lr] = p2;
            }
        }
        __syncthreads();

#pragma unroll
        for (int ks = 0; ks < 2; ++ks) {
            const short8b b1 = *reinterpret_cast<const short8b*>(
                &Vtl[0][w * 16 + lr][ks * 32 + lg * 8]);
            const short8b b2 = *reinterpret_cast<const short8b*>(
                &Vtl[1][w * 16 + lr][ks * 32 + lg * 8]);
#pragma unroll
            for (int qt = 0; qt < 3; ++qt) {
                const short8b a1 = *reinterpret_cast<const short8b*>(
                    &Ks[0][qt * 16 + lr][ks * 32 + lg * 8]);
                const short8b a2 = *reinterpret_cast<const short8b*>(
                    &Ks[1][qt * 16 + lr][ks * 32 + lg * 8]);
                pvacc[qt] = __builtin_amdgcn_mfma_f32_16x16x32_bf16(a1, b1, pvacc[qt], 0, 0, 0);
                pvacc[qt] = __builtin_amdgcn_mfma_f32_16x16x32_bf16(a2, b1, pvacc[qt], 0, 0, 0);
                pvacc[qt] = __builtin_amdgcn_mfma_f32_16x16x32_bf16(a1, b2, pvacc[qt], 0, 0, 0);
            }
        }
    }

#pragma unroll
    for (int qt = 0; qt < 3; ++qt) {
#pragma unroll
        for (int r = 0; r < 4; ++r) {
            const int q = qt * 16 + lg * 4 + r;
            if (q < NTOP)
                atomicAdd(&uacc[((size_t)bh * NTOP + q) * DHD + w * 16 + lr],
                          pvacc[qt][r]);
        }
    }
    if (tid < NTOP) atomicAdd(&wsum[bh * NTOP + tid], wsl[tid]);

    // out-broadcast epilogue: block (bh,seg) streams its 2048-float4 slice
    {
        const int blkid = bh * NSEG + seg;               // 0..511
        const int base4 = blkid * 2048;                  // of 2^20 total
        for (int i = base4 + tid; i < base4 + 2048; i += 256) {
            const int row = i >> 7;
            const int b = row >> 11;
            const int c = i & 127;
            reinterpret_cast<float4*>(out)[i] =
                reinterpret_cast<const float4*>(meanout)[b * 128 + c];
        }
    }
}

// ---------------------------------------------------------------------------
// K5: scatter-add selected rows: out[b,l,:] += delta @ Wo_h^T, delta inline.
// ---------------------------------------------------------------------------
__global__ __launch_bounds__(128) void out_scatter(
    const int* __restrict__ topidx, const float* __restrict__ wsum,
    const float* __restrict__ uacc, const float* __restrict__ VmeanRaw,
    const float* __restrict__ Wo, float* __restrict__ out)
{
    const int bh = blockIdx.x;
    const int u  = blockIdx.y;
    const int b = bh >> 3, h = bh & 7;
    const int l = topidx[bh * NTOP + u];

    __shared__ float dl[DHD];
    if (threadIdx.x < DHD) {
        const float inv = 1.0f / wsum[bh * NTOP + u];
        const float vm = VmeanRaw[bh * DHD + threadIdx.x] * (1.0f / (float)LSEQ);
        dl[threadIdx.x] =
            uacc[((size_t)bh * NTOP + u) * DHD + threadIdx.x] * inv - vm;
    }
    __syncthreads();

    float* orow = out + ((size_t)b * LSEQ + l) * DMODEL;
#pragma unroll
    for (int c = 0; c < 4; ++c) {
        const int n = threadIdx.x * 4 + c;
        const float4* wr4 = reinterpret_cast<const float4*>(
            Wo + (size_t)n * DMODEL + h * DHD);
        float a = 0.f;
#pragma unroll
        for (int dd = 0; dd < 16; ++dd) {
            const float4 wv = wr4[dd];
            a += dl[dd * 4 + 0] * wv.x + dl[dd * 4 + 1] * wv.y +
                 dl[dd * 4 + 2] * wv.z + dl[dd * 4 + 3] * wv.w;
        }
        atomicAdd(&orow[n], a);
    }
}

// ---------------------------------------------------------------------------
extern "C" void kernel_launch(void* const* d_in, const int* in_sizes, int n_in,
                              void* d_out, int out_size, void* d_ws, size_t ws_size,
                              hipStream_t stream)
{
    (void)in_sizes; (void)n_in; (void)out_size; (void)ws_size;
    const float* x     = (const float*)d_in[0];
    const float* ctxin = (const float*)d_in[1];
    const float* Wq    = (const float*)d_in[2];
    const float* bq    = (const float*)d_in[3];
    const float* Wk    = (const float*)d_in[4];
    const float* bk    = (const float*)d_in[5];
    const float* Wv    = (const float*)d_in[6];
    const float* bv    = (const float*)d_in[7];
    const float* Wo    = (const float*)d_in[8];
    const float* bo    = (const float*)d_in[9];
    const int*   idxs  = (const int*)d_in[10];
    float* out = (float*)d_out;

    char* ws = (char*)d_ws;
    size_t off = 0;
    auto alloc = [&](size_t bytes) -> void* {
        void* p = ws + off;
        off += (bytes + 255) & ~(size_t)255;
        return p;
    };

    const size_t qkv_bytes = (size_t)BATCH * NH * LSEQ * DHD * sizeof(float);
    float*         Qt       = (float*)alloc(qkv_bytes);
    float*         Kt       = (float*)alloc(qkv_bytes);
    float*         Vt       = (float*)alloc(qkv_bytes);
    float*         Mbuf     = (float*)alloc((size_t)BATCH * NH * LSEQ * sizeof(float));
    float*         VmeanRaw = (float*)alloc((size_t)BATCH * NH * DHD * sizeof(float));
    float*         meanout  = (float*)alloc((size_t)BATCH * DMODEL * sizeof(float));
    int*           topidx   = (int*)alloc((size_t)BATCH * NH * NTOP * sizeof(int));
    float*         wsum     = (float*)alloc((size_t)BATCH * NH * NTOP * sizeof(float));
    float*         uacc     = (float*)alloc((size_t)BATCH * NH * NTOP * DHD * sizeof(float));
    u16*           xsP      = (u16*)alloc(ASTRIDE * 3 * 2);
    u16*           csP      = (u16*)alloc(ASTRIDE * 3 * 2);
    u16*           wqP      = (u16*)alloc(WSTRIDE * 3 * 2);
    u16*           wkP      = (u16*)alloc(WSTRIDE * 3 * 2);
    u16*           wvP      = (u16*)alloc(WSTRIDE * 3 * 2);

    split3_all<<<2048, 256, 0, stream>>>(x, ctxin, Wq, Wk, Wv,
                                         xsP, csP, wqP, wkP, wvP,
                                         VmeanRaw, uacc, wsum);

    gemm_all<<<dim3(256, 3), 256, 0, stream>>>(
        xsP, csP, wqP, wkP, wvP, bq, bk, bv, Qt, Kt, Vt, VmeanRaw);

    score_kernel<<<(BATCH * NH * LSEQ) / 4, 256, 0, stream>>>(
        Qt, Kt, idxs, Mbuf);

    topk_kernel<<<36, 256, 0, stream>>>(
        Mbuf, topidx, VmeanRaw, Wo, bo, meanout);

    attn_partial<<<dim3(BATCH * NH, NSEG), 256, 0, stream>>>(
        Qt, Kt, Vt, topidx, wsum, uacc, meanout, out);

    out_scatter<<<dim3(BATCH * NH, NTOP), 128, 0, stream>>>(
        topidx, wsum, uacc, VmeanRaw, Wo, out);
}